// Round 3
// baseline (172.740 us; speedup 1.0000x reference)
//
#include <hip/hip_runtime.h>

#define IN_FEAT    128
#define EDGE_EMBED 32
// W1_w: [256, 256] row-major. W2_w: [2, 288] row-major.
//
// Factorization (no nonlinearity anywhere):
//   score[i,j] = pu[src[i]][j] + pv[dst[i]][j] + sum_m e[i,m]*W2_w[j,256+m] + bias[j]
//   pu[n][j] = sum_{f<128} h[n,f] * M[f,j],  pv uses M[128+f,j]
//   M[f,j]   = sum_k W1_w[k,f] * W2_w[j,k]
//   bias[j]  = sum_k W1_b[k]   * W2_w[j,k] + W2_b[j]
//
// ws layout (floats):
//   [0..511]      M[f*2+j]
//   [512..513]    bias
//   [1024 ..]     pu[n*2+j]   (N*2 floats)
//   [1024+2N ..]  pv[n*2+j]   (N*2 floats)

// ---------------------------------------------------------------------------
// Kernel A: collapse W1/W2 into M + bias. 1024 threads: 256 f-columns x
// 4 k-chunks, LDS reduce — 4x the memory parallelism of the R2 version.
// ---------------------------------------------------------------------------
__global__ __launch_bounds__(1024) void precompute_kernel(
    const float* __restrict__ W1_w, const float* __restrict__ W1_b,
    const float* __restrict__ W2_w, const float* __restrict__ W2_b,
    float* __restrict__ ws) {
    __shared__ float part[4][512];
    const int f = threadIdx.x & 255;
    const int chunk = threadIdx.x >> 8;   // 0..3
    float m0 = 0.f, m1 = 0.f;
#pragma unroll 16
    for (int kk = 0; kk < 64; ++kk) {
        const int k = chunk * 64 + kk;
        const float w1 = W1_w[k * 256 + f];   // coalesced across f
        m0 = fmaf(w1, W2_w[k], m0);
        m1 = fmaf(w1, W2_w[288 + k], m1);
    }
    part[chunk][f * 2 + 0] = m0;
    part[chunk][f * 2 + 1] = m1;
    __syncthreads();
    if (chunk == 0) {
        ws[f * 2 + 0] = part[0][f * 2] + part[1][f * 2] + part[2][f * 2] + part[3][f * 2];
        ws[f * 2 + 1] = part[0][f * 2 + 1] + part[1][f * 2 + 1] + part[2][f * 2 + 1] + part[3][f * 2 + 1];
    }
    // bias: first 64 threads, 4 elems/lane, 64-lane butterfly
    if (threadIdx.x < 64) {
        const int t = threadIdx.x;
        float b0 = 0.f, b1 = 0.f;
#pragma unroll
        for (int m = 0; m < 4; ++m) {
            const int k = t + 64 * m;
            const float wb = W1_b[k];
            b0 = fmaf(wb, W2_w[k], b0);
            b1 = fmaf(wb, W2_w[288 + k], b1);
        }
#pragma unroll
        for (int m = 32; m >= 1; m >>= 1) {
            b0 += __shfl_xor(b0, m);
            b1 += __shfl_xor(b1, m);
        }
        if (t == 0) {
            ws[512] = b0 + W2_b[0];
            ws[513] = b1 + W2_b[1];
        }
    }
}

// ---------------------------------------------------------------------------
// Kernel B: per-node projections. 32 lanes per node row (one float4/lane =
// one coalesced 512 B row), 5-step shuffle reduce. Reads h once: 25.6 MB.
// ---------------------------------------------------------------------------
__global__ __launch_bounds__(256, 8) void node_proj_kernel(
    const float* __restrict__ h, const float* __restrict__ ws,
    float* __restrict__ pu, float* __restrict__ pv, int N) {
    const int p = threadIdx.x & 31;
    const int node = blockIdx.x * 8 + (threadIdx.x >> 5);
    if (node >= N) return;

    const float4 muA = *(const float4*)(ws + p * 8);
    const float4 muB = *(const float4*)(ws + p * 8 + 4);
    const float4 mvA = *(const float4*)(ws + 256 + p * 8);
    const float4 mvB = *(const float4*)(ws + 256 + p * 8 + 4);

    const float4 hr = *(const float4*)(h + (size_t)node * IN_FEAT + p * 4);

    float u0 = hr.x * muA.x, u1 = hr.x * muA.y;
    u0 = fmaf(hr.y, muA.z, u0); u1 = fmaf(hr.y, muA.w, u1);
    u0 = fmaf(hr.z, muB.x, u0); u1 = fmaf(hr.z, muB.y, u1);
    u0 = fmaf(hr.w, muB.z, u0); u1 = fmaf(hr.w, muB.w, u1);
    float v0 = hr.x * mvA.x, v1 = hr.x * mvA.y;
    v0 = fmaf(hr.y, mvA.z, v0); v1 = fmaf(hr.y, mvA.w, v1);
    v0 = fmaf(hr.z, mvB.x, v0); v1 = fmaf(hr.z, mvB.y, v1);
    v0 = fmaf(hr.w, mvB.z, v0); v1 = fmaf(hr.w, mvB.w, v1);

#pragma unroll
    for (int m = 16; m >= 1; m >>= 1) {
        u0 += __shfl_xor(u0, m); u1 += __shfl_xor(u1, m);
        v0 += __shfl_xor(v0, m); v1 += __shfl_xor(v1, m);
    }
    if (p == 0) {
        *(float2*)(pu + (size_t)node * 2) = make_float2(u0, u1);
        *(float2*)(pv + (size_t)node * 2) = make_float2(v0, v1);
    }
}

// ---------------------------------------------------------------------------
// Kernel C: edge scores — ONE EDGE PER LANE. No divergence, no shuffles.
// - src/dst: coalesced dword loads (all 64 lanes)
// - pu/pv: per-lane 8 B gathers from 800 KB L2-resident tables
// - e: 8 per-lane float4 loads (128 B/lane; every 128 B line fetched once)
// - W2_w e-weights: lane-uniform addresses -> SGPRs (free VALU operand)
// - out: coalesced float2 store (512 B/wave)
// ---------------------------------------------------------------------------
__global__ __launch_bounds__(256, 4) void edge_score_kernel(
    const int* __restrict__ src, const int* __restrict__ dst,
    const float* __restrict__ e, const float* __restrict__ W2_w,
    const float* __restrict__ ws, const float* __restrict__ pu,
    const float* __restrict__ pv, float* __restrict__ out, int E) {
    const int i = blockIdx.x * blockDim.x + threadIdx.x;
    if (i >= E) return;

    const int s = src[i];
    const int d = dst[i];
    const float2 u = *(const float2*)(pu + (size_t)s * 2);
    const float2 v = *(const float2*)(pv + (size_t)d * 2);

    float acc0 = u.x + v.x + ws[512];
    float acc1 = u.y + v.y + ws[513];

    const float* ep = e + (size_t)i * EDGE_EMBED;
#pragma unroll
    for (int c4 = 0; c4 < 8; ++c4) {
        const float4 ev = *(const float4*)(ep + c4 * 4);
        const float4 wa = *(const float4*)(W2_w + 256 + c4 * 4);  // uniform -> SGPR
        const float4 wb = *(const float4*)(W2_w + 544 + c4 * 4);  // uniform -> SGPR
        acc0 = fmaf(ev.x, wa.x, acc0); acc1 = fmaf(ev.x, wb.x, acc1);
        acc0 = fmaf(ev.y, wa.y, acc0); acc1 = fmaf(ev.y, wb.y, acc1);
        acc0 = fmaf(ev.z, wa.z, acc0); acc1 = fmaf(ev.z, wb.z, acc1);
        acc0 = fmaf(ev.w, wa.w, acc0); acc1 = fmaf(ev.w, wb.w, acc1);
    }
    *(float2*)(out + (size_t)i * 2) = make_float2(acc0, acc1);
}

extern "C" void kernel_launch(void* const* d_in, const int* in_sizes, int n_in,
                              void* d_out, int out_size, void* d_ws, size_t ws_size,
                              hipStream_t stream) {
    const float* h    = (const float*)d_in[0];
    const int*   src  = (const int*)d_in[1];
    const int*   dst  = (const int*)d_in[2];
    const float* e    = (const float*)d_in[3];
    const float* W1_w = (const float*)d_in[4];
    const float* W1_b = (const float*)d_in[5];
    const float* W2_w = (const float*)d_in[6];
    const float* W2_b = (const float*)d_in[7];
    float* out = (float*)d_out;
    float* ws  = (float*)d_ws;

    const int E = in_sizes[1];
    const int N = in_sizes[0] / IN_FEAT;

    float* pu = ws + 1024;
    float* pv = ws + 1024 + (size_t)N * 2;

    precompute_kernel<<<1, 1024, 0, stream>>>(W1_w, W1_b, W2_w, W2_b, ws);
    node_proj_kernel<<<(N + 7) / 8, 256, 0, stream>>>(h, ws, pu, pv, N);
    edge_score_kernel<<<(E + 255) / 256, 256, 0, stream>>>(src, dst, e, W2_w, ws,
                                                           pu, pv, out, E);
}